// Round 1
// baseline (1868.642 us; speedup 1.0000x reference)
//
#include <hip/hip_runtime.h>

#define NN 50000
#define NE 500000
#define DD 128
#define KK 25000

// ---------------- zero init ----------------
__global__ void k_zero(double* zd, int nd, int* zi, int ni) {
  int i = blockIdx.x * blockDim.x + threadIdx.x;
  int stride = gridDim.x * blockDim.x;
  for (int k = i; k < nd; k += stride) zd[k] = 0.0;
  for (int k = i; k < ni; k += stride) zi[k] = 0;
}

// ---------------- small composed matrices ----------------
// Ck_b = A_b @ wk_w, Dk_b = B_b @ wk_w  (A_b = W_bases[b][0:128], B_b = rows 128:256)
// vecs = [A0@wv_w, A1@wv_w, B0@wv_w, B1@wv_w] each length 128
__global__ void k_smallmats(const float* Wb, const float* wkw, const float* wvw,
                            double* Ck0, double* Ck1, double* Dk0, double* Dk1,
                            double* vecs) {
  int b = blockIdx.x, tid = threadIdx.x;
  if (b < 4) {
    int basis = b & 1;
    int rowoff = (b >> 1) * DD;
    double* outp = (b == 0) ? Ck0 : ((b == 1) ? Ck1 : ((b == 2) ? Dk0 : Dk1));
    for (int idx = tid; idx < DD * DD; idx += blockDim.x) {
      int i = idx >> 7, t = idx & 127;
      const float* wrow = Wb + (size_t)(basis * 2 * DD + rowoff + i) * DD;
      double s = 0.0;
      for (int m = 0; m < DD; m++) s += (double)wrow[m] * (double)wkw[m * DD + t];
      outp[idx] = s;
    }
  } else {
    for (int idx = tid; idx < 4 * DD; idx += blockDim.x) {
      int which = idx >> 7, i = idx & 127;
      int basis = which & 1, rowoff = (which >> 1) * DD;
      const float* wrow = Wb + (size_t)(basis * 2 * DD + rowoff + i) * DD;
      double s = 0.0;
      for (int m = 0; m < DD; m++) s += (double)wrow[m] * (double)wvw[m];
      vecs[which * DD + i] = s;
    }
  }
}

// ---------------- node-level matvec: out[n][:] = h[n] @ M (+bias)  or  t[n] = (h[n]@M)·q[n]
__global__ void __launch_bounds__(256) k_matnode(const float* h, const float* matf,
                                                 const double* matd, const float* bias,
                                                 const double* q_in, double* outv,
                                                 double* outt) {
  __shared__ float hs[32 * DD];
  __shared__ double red[4];
  int tid = threadIdx.x;
  int n0 = blockIdx.x * 32;
  for (int idx = tid; idx < 32 * DD; idx += 256) {
    int n = n0 + (idx >> 7);
    hs[idx] = (n < NN) ? h[(size_t)n * DD + (idx & 127)] : 0.0f;
  }
  __syncthreads();
  int col = tid & 127, half = tid >> 7;
  double acc[16];
#pragma unroll
  for (int j = 0; j < 16; j++) acc[j] = 0.0;
  for (int k4 = 0; k4 < DD / 4; k4++) {
    double m0, m1, m2, m3;
    if (matf) {
      m0 = (double)matf[(4 * k4 + 0) * DD + col];
      m1 = (double)matf[(4 * k4 + 1) * DD + col];
      m2 = (double)matf[(4 * k4 + 2) * DD + col];
      m3 = (double)matf[(4 * k4 + 3) * DD + col];
    } else {
      m0 = matd[(4 * k4 + 0) * DD + col];
      m1 = matd[(4 * k4 + 1) * DD + col];
      m2 = matd[(4 * k4 + 2) * DD + col];
      m3 = matd[(4 * k4 + 3) * DD + col];
    }
#pragma unroll
    for (int j = 0; j < 16; j++) {
      const float4 hv = *(const float4*)&hs[(half * 16 + j) * DD + 4 * k4];
      acc[j] += (double)hv.x * m0 + (double)hv.y * m1 + (double)hv.z * m2 + (double)hv.w * m3;
    }
  }
  if (!outt) {
    for (int j = 0; j < 16; j++) {
      int n = n0 + half * 16 + j;
      if (n < NN) {
        double v = acc[j];
        if (bias) v += (double)bias[col];
        outv[(size_t)n * DD + col] = v;
      }
    }
  } else {
    int lane = tid & 63, wid = tid >> 6;
    for (int j = 0; j < 16; j++) {
      int n = n0 + half * 16 + j;
      double v = (n < NN) ? acc[j] * q_in[(size_t)n * DD + col] : 0.0;
      for (int off = 32; off; off >>= 1) v += __shfl_xor(v, off);
      if (lane == 0) red[wid] = v;
      __syncthreads();
      if (tid == 0) { int na = n0 + j;      if (na < NN) outt[na] = red[0] + red[1]; }
      if (tid == 1) { int nb = n0 + 16 + j; if (nb < NN) outt[nb] = red[2] + red[3]; }
      __syncthreads();
    }
  }
}

// ---------------- per-node scalars: av_b, bv_b, u = wk_b·q[n], self_y ----------------
__global__ void k_nodescalars(const float* h, const double* q, const double* vecs,
                              const float* wkb, const float* coef, const float* wvb,
                              double* av0, double* av1, double* bv0, double* bv1,
                              double* u, double* selfy) {
  int wid = threadIdx.x >> 6, lane = threadIdx.x & 63;
  int n = blockIdx.x * 4 + wid;
  if (n >= NN) return;
  const double* avv0 = vecs;
  const double* avv1 = vecs + DD;
  const double* bvv0 = vecs + 2 * DD;
  const double* bvv1 = vecs + 3 * DD;
  double h0 = (double)h[(size_t)n * DD + lane], h1 = (double)h[(size_t)n * DD + 64 + lane];
  double q0 = q[(size_t)n * DD + lane], q1 = q[(size_t)n * DD + 64 + lane];
  double a0 = h0 * avv0[lane] + h1 * avv0[64 + lane];
  double a1 = h0 * avv1[lane] + h1 * avv1[64 + lane];
  double b0 = h0 * bvv0[lane] + h1 * bvv0[64 + lane];
  double b1 = h0 * bvv1[lane] + h1 * bvv1[64 + lane];
  double uu = q0 * (double)wkb[lane] + q1 * (double)wkb[64 + lane];
  for (int off = 32; off; off >>= 1) {
    a0 += __shfl_xor(a0, off); a1 += __shfl_xor(a1, off);
    b0 += __shfl_xor(b0, off); b1 += __shfl_xor(b1, off);
    uu += __shfl_xor(uu, off);
  }
  if (lane == 0) {
    av0[n] = a0; av1[n] = a1; bv0[n] = b0; bv1[n] = b1; u[n] = uu;
    double c40 = (double)coef[4 * 2 + 0], c41 = (double)coef[4 * 2 + 1];
    selfy[n] = c40 * (a0 + b0) + c41 * (a1 + b1) + (double)wvb[0];
  }
}

// ---------------- edge kernel: both directions, atomically aggregate ----------------
__global__ void k_edges(const int* src, const int* dst, const int* et, const float* coef,
                        const float* wvb, const double* Pk0, const double* Pk1,
                        const double* q, const double* t0, const double* t1,
                        const double* u, const double* av0, const double* av1,
                        const double* bv0, const double* bv1, double* wvin, double* zin,
                        double* wvout, double* zout) {
  int wid = threadIdx.x >> 6, lane = threadIdx.x & 63;
  long e = (long)blockIdx.x * 4 + wid;
  if (e >= NE) return;
  int s = src[e], d = dst[e], t = et[e];
  double c0 = (double)coef[t * 2], c1 = (double)coef[t * 2 + 1];
  size_t sb = (size_t)s * DD, db = (size_t)d * DD;
  double p0s0 = Pk0[sb + lane], p0s1 = Pk0[sb + 64 + lane];
  double p1s0 = Pk1[sb + lane], p1s1 = Pk1[sb + 64 + lane];
  double p0d0 = Pk0[db + lane], p0d1 = Pk0[db + 64 + lane];
  double p1d0 = Pk1[db + lane], p1d1 = Pk1[db + 64 + lane];
  double qs0 = q[sb + lane], qs1 = q[sb + 64 + lane];
  double qd0 = q[db + lane], qd1 = q[db + 64 + lane];
  double df = (c0 * p0s0 + c1 * p1s0) * qd0 + (c0 * p0s1 + c1 * p1s1) * qd1;
  double dr = (c0 * p0d0 + c1 * p1d0) * qs0 + (c0 * p0d1 + c1 * p1d1) * qs1;
  for (int off = 32; off; off >>= 1) {
    df += __shfl_xor(df, off);
    dr += __shfl_xor(dr, off);
  }
  if (lane == 0) {
    const double scale = sqrt(128.0);
    double wvbd = (double)wvb[0];
    double sf = (df + c0 * t0[d] + c1 * t1[d] + u[d]) / scale;
    sf = fmin(fmax(sf, -10.0), 10.0);
    double ef = exp(sf);
    double nvf = c0 * (av0[s] + bv0[d]) + c1 * (av1[s] + bv1[d]) + wvbd;
    atomicAdd(&wvin[d], ef * nvf);
    atomicAdd(&zin[d], ef);
    double sr = (dr + c0 * t0[s] + c1 * t1[s] + u[s]) / scale;
    sr = fmin(fmax(sr, -10.0), 10.0);
    double er = exp(sr);
    double nvr = c0 * (av0[d] + bv0[s]) + c1 * (av1[d] + bv1[s]) + wvbd;
    atomicAdd(&wvout[s], er * nvr);
    atomicAdd(&zout[s], er);
  }
}

// ---------------- y = in_y + out_y + self_y ----------------
__global__ void k_y(const double* wvin, const double* zin, const double* wvout,
                    const double* zout, const double* selfy, double* y) {
  int n = blockIdx.x * blockDim.x + threadIdx.x;
  if (n < NN) y[n] = wvin[n] / (zin[n] + 1e-6) + wvout[n] / (zout[n] + 1e-6) + selfy[n];
}

// ---------------- exact descending rank (top_k + stable tie semantics) ----------------
#define JCHUNK 6250
__global__ void k_rank(const double* y, int* rank) {
  __shared__ double ys[2048];
  int i = blockIdx.x * 256 + threadIdx.x;
  double yi = (i < NN) ? y[i] : 0.0;
  int jbase = blockIdx.y * JCHUNK;
  int jend = jbase + JCHUNK;
  int cnt = 0;
  for (int base = jbase; base < jend; base += 2048) {
    int m = min(2048, jend - base);
    for (int jj = threadIdx.x; jj < m; jj += 256) ys[jj] = y[base + jj];
    __syncthreads();
#pragma unroll 4
    for (int jj = 0; jj < m; jj++) {
      double yj = ys[jj];
      int j = base + jj;
      bool c = (j < i) ? (yj >= yi) : (yj > yi);
      cnt += c ? 1 : 0;
    }
    __syncthreads();
  }
  if (i < NN) atomicAdd(&rank[i], cnt);
}

// ---------------- selection scatter ----------------
__global__ void k_bcnt(const int* rank, int* bcnt) {
  __shared__ int sh[256];
  int i = blockIdx.x * 256 + threadIdx.x;
  int f = (i < NN && rank[i] < KK) ? 1 : 0;
  sh[threadIdx.x] = f;
  __syncthreads();
  for (int off = 128; off; off >>= 1) {
    if (threadIdx.x < off) sh[threadIdx.x] += sh[threadIdx.x + off];
    __syncthreads();
  }
  if (threadIdx.x == 0) bcnt[blockIdx.x] = sh[0];
}

__global__ void k_scan(int* bcnt, int nb) {
  if (threadIdx.x == 0 && blockIdx.x == 0) {
    int run = 0;
    for (int b = 0; b < nb; b++) { int t = bcnt[b]; bcnt[b] = run; run += t; }
  }
}

__global__ void k_scatter(const int* rank, const int* bcnt, const double* y,
                          float* out_ids, int* selp, double* sig) {
  __shared__ int sh[256];
  int i = blockIdx.x * 256 + threadIdx.x;
  int f = (i < NN && rank[i] < KK) ? 1 : 0;
  sh[threadIdx.x] = f;
  __syncthreads();
  for (int off = 1; off < 256; off <<= 1) {
    int v = (threadIdx.x >= off) ? sh[threadIdx.x - off] : 0;
    __syncthreads();
    sh[threadIdx.x] += v;
    __syncthreads();
  }
  if (f) {
    int slot = bcnt[blockIdx.x] + sh[threadIdx.x] - 1;
    out_ids[slot] = (float)i;
    int p = rank[i];             // position in descending-y list = sel index
    selp[slot] = p;
    sig[slot] = 1.0 / (1.0 + exp(-y[p]));   // note: y of NODE p (faithful to source)
  }
}

__global__ void k_outh(const float* h, const int* selp, const double* sig, float* out) {
  long idx = (long)blockIdx.x * 256 + threadIdx.x;
  if (idx >= (long)KK * DD) return;
  int slot = (int)(idx >> 7), c = (int)(idx & 127);
  int p = selp[slot];
  out[KK + idx] = (float)((double)h[(size_t)p * DD + c] * sig[slot]);
}

extern "C" void kernel_launch(void* const* d_in, const int* in_sizes, int n_in,
                              void* d_out, int out_size, void* d_ws, size_t ws_size,
                              hipStream_t stream) {
  const float* h = (const float*)d_in[0];
  const int* src = (const int*)d_in[1];
  const int* dst = (const int*)d_in[2];
  const int* etype = (const int*)d_in[3];
  const float* Wb = (const float*)d_in[4];
  const float* coef = (const float*)d_in[5];
  const float* wqw = (const float*)d_in[6];
  const float* wqb = (const float*)d_in[7];
  const float* wkw = (const float*)d_in[8];
  const float* wkb = (const float*)d_in[9];
  const float* wvw = (const float*)d_in[10];
  const float* wvb = (const float*)d_in[11];
  float* out = (float*)d_out;

  double* W = (double*)d_ws;
  size_t o = 0;
  double* q = W + o;   o += (size_t)NN * DD;
  double* Pk0 = W + o; o += (size_t)NN * DD;
  double* Pk1 = W + o; o += (size_t)NN * DD;
  double* Ck0 = W + o; o += DD * DD;
  double* Ck1 = W + o; o += DD * DD;
  double* Dk0 = W + o; o += DD * DD;
  double* Dk1 = W + o; o += DD * DD;
  double* vecs = W + o; o += 4 * DD;
  double* t0 = W + o;  o += NN;
  double* t1 = W + o;  o += NN;
  double* av0 = W + o; o += NN;
  double* av1 = W + o; o += NN;
  double* bv0 = W + o; o += NN;
  double* bv1 = W + o; o += NN;
  double* u = W + o;   o += NN;
  double* selfy = W + o; o += NN;
  double* wvin = W + o;  o += NN;  // zero-init region start (4*NN contiguous)
  double* zin = W + o;   o += NN;
  double* wvout = W + o; o += NN;
  double* zout = W + o;  o += NN;
  double* y = W + o;     o += NN;
  double* sig = W + o;   o += KK;
  int* ibase = (int*)(W + o);
  int* rank = ibase;
  int* bcnt = ibase + NN;
  int* selp = ibase + NN + 256;

  int nb = (NN + 255) / 256;  // 196

  k_zero<<<512, 256, 0, stream>>>(wvin, 4 * NN, rank, NN);
  k_smallmats<<<5, 256, 0, stream>>>(Wb, wkw, wvw, Ck0, Ck1, Dk0, Dk1, vecs);
  int gx = (NN + 31) / 32;
  k_matnode<<<gx, 256, 0, stream>>>(h, wqw, nullptr, wqb, nullptr, q, nullptr);
  k_matnode<<<gx, 256, 0, stream>>>(h, nullptr, Ck0, nullptr, nullptr, Pk0, nullptr);
  k_matnode<<<gx, 256, 0, stream>>>(h, nullptr, Ck1, nullptr, nullptr, Pk1, nullptr);
  k_matnode<<<gx, 256, 0, stream>>>(h, nullptr, Dk0, nullptr, q, nullptr, t0);
  k_matnode<<<gx, 256, 0, stream>>>(h, nullptr, Dk1, nullptr, q, nullptr, t1);
  k_nodescalars<<<(NN + 3) / 4, 256, 0, stream>>>(h, q, vecs, wkb, coef, wvb, av0, av1,
                                                  bv0, bv1, u, selfy);
  k_edges<<<NE / 4, 256, 0, stream>>>(src, dst, etype, coef, wvb, Pk0, Pk1, q, t0, t1, u,
                                      av0, av1, bv0, bv1, wvin, zin, wvout, zout);
  k_y<<<nb, 256, 0, stream>>>(wvin, zin, wvout, zout, selfy, y);
  k_rank<<<dim3(nb, 8), 256, 0, stream>>>(y, rank);
  k_bcnt<<<nb, 256, 0, stream>>>(rank, bcnt);
  k_scan<<<1, 64, 0, stream>>>(bcnt, nb);
  k_scatter<<<nb, 256, 0, stream>>>(rank, bcnt, y, out, selp, sig);
  k_outh<<<(KK * DD) / 256, 256, 0, stream>>>(h, selp, sig, out);
}

// Round 2
// 1286.117 us; speedup vs baseline: 1.4529x; 1.4529x over previous
//
#include <hip/hip_runtime.h>

#define NN 50000
#define NE 500000
#define DD 128
#define KK 25000

// ---------------- zero init ----------------
__global__ void k_zero(float* zf, int nf, int* zi, int ni) {
  int i = blockIdx.x * blockDim.x + threadIdx.x;
  int stride = gridDim.x * blockDim.x;
  for (int k = i; k < nf; k += stride) zf[k] = 0.0f;
  for (int k = i; k < ni; k += stride) zi[k] = 0;
}

// ---------------- small composed matrices (f32) ----------------
// Ck_b = A_b @ wk_w, Dk_b = B_b @ wk_w ; vecs = [A0,A1,B0,B1] @ wv_w
__global__ void k_smallmats(const float* Wb, const float* wkw, const float* wvw,
                            float* Ck0, float* Ck1, float* Dk0, float* Dk1,
                            float* vecs) {
  int b = blockIdx.x, tid = threadIdx.x;
  if (b < 4) {
    int basis = b & 1;
    int rowoff = (b >> 1) * DD;
    float* outp = (b == 0) ? Ck0 : ((b == 1) ? Ck1 : ((b == 2) ? Dk0 : Dk1));
    for (int idx = tid; idx < DD * DD; idx += blockDim.x) {
      int i = idx >> 7, t = idx & 127;
      const float* wrow = Wb + (size_t)(basis * 2 * DD + rowoff + i) * DD;
      float s = 0.0f;
      for (int m = 0; m < DD; m++) s += wrow[m] * wkw[m * DD + t];
      outp[idx] = s;
    }
  } else {
    for (int idx = tid; idx < 4 * DD; idx += blockDim.x) {
      int which = idx >> 7, i = idx & 127;
      int basis = which & 1, rowoff = (which >> 1) * DD;
      const float* wrow = Wb + (size_t)(basis * 2 * DD + rowoff + i) * DD;
      float s = 0.0f;
      for (int m = 0; m < DD; m++) s += wrow[m] * wvw[m];
      vecs[which * DD + i] = s;
    }
  }
}

// ---------------- node-level matvec: outv[n][:] = h[n]@M (+bias), or outt[n]=(h[n]@M)·q[n]
__global__ void __launch_bounds__(256) k_matnode(const float* h, const float* matf,
                                                 const float* bias, const float* q_in,
                                                 float* outv, float* outt) {
  __shared__ float hs[32 * DD];
  __shared__ float red[4];
  int tid = threadIdx.x;
  int n0 = blockIdx.x * 32;
  for (int idx = tid; idx < 32 * DD; idx += 256) {
    int n = n0 + (idx >> 7);
    hs[idx] = (n < NN) ? h[(size_t)n * DD + (idx & 127)] : 0.0f;
  }
  __syncthreads();
  int col = tid & 127, half = tid >> 7;
  float acc[16];
#pragma unroll
  for (int j = 0; j < 16; j++) acc[j] = 0.0f;
  for (int k4 = 0; k4 < DD / 4; k4++) {
    float m0 = matf[(4 * k4 + 0) * DD + col];
    float m1 = matf[(4 * k4 + 1) * DD + col];
    float m2 = matf[(4 * k4 + 2) * DD + col];
    float m3 = matf[(4 * k4 + 3) * DD + col];
#pragma unroll
    for (int j = 0; j < 16; j++) {
      const float4 hv = *(const float4*)&hs[(half * 16 + j) * DD + 4 * k4];
      acc[j] += hv.x * m0 + hv.y * m1 + hv.z * m2 + hv.w * m3;
    }
  }
  if (!outt) {
    for (int j = 0; j < 16; j++) {
      int n = n0 + half * 16 + j;
      if (n < NN) {
        float v = acc[j];
        if (bias) v += bias[col];
        outv[(size_t)n * DD + col] = v;
      }
    }
  } else {
    int lane = tid & 63, wid = tid >> 6;
    for (int j = 0; j < 16; j++) {
      int n = n0 + half * 16 + j;
      float v = (n < NN) ? acc[j] * q_in[(size_t)n * DD + col] : 0.0f;
      for (int off = 32; off; off >>= 1) v += __shfl_xor(v, off);
      if (lane == 0) red[wid] = v;
      __syncthreads();
      if (tid == 0) { int na = n0 + j;      if (na < NN) outt[na] = red[0] + red[1]; }
      if (tid == 1) { int nb2 = n0 + 16 + j; if (nb2 < NN) outt[nb2] = red[2] + red[3]; }
      __syncthreads();
    }
  }
}

// ---------------- per-node scalars ----------------
__global__ void k_nodescalars(const float* h, const float* q, const float* vecs,
                              const float* wkb, const float* coef, const float* wvb,
                              float* av0, float* av1, float* bv0, float* bv1,
                              float* u, float* selfy) {
  int wid = threadIdx.x >> 6, lane = threadIdx.x & 63;
  int n = blockIdx.x * 4 + wid;
  if (n >= NN) return;
  const float* avv0 = vecs;
  const float* avv1 = vecs + DD;
  const float* bvv0 = vecs + 2 * DD;
  const float* bvv1 = vecs + 3 * DD;
  float h0 = h[(size_t)n * DD + lane], h1 = h[(size_t)n * DD + 64 + lane];
  float q0 = q[(size_t)n * DD + lane], q1 = q[(size_t)n * DD + 64 + lane];
  float a0 = h0 * avv0[lane] + h1 * avv0[64 + lane];
  float a1 = h0 * avv1[lane] + h1 * avv1[64 + lane];
  float b0 = h0 * bvv0[lane] + h1 * bvv0[64 + lane];
  float b1 = h0 * bvv1[lane] + h1 * bvv1[64 + lane];
  float uu = q0 * wkb[lane] + q1 * wkb[64 + lane];
  for (int off = 32; off; off >>= 1) {
    a0 += __shfl_xor(a0, off); a1 += __shfl_xor(a1, off);
    b0 += __shfl_xor(b0, off); b1 += __shfl_xor(b1, off);
    uu += __shfl_xor(uu, off);
  }
  if (lane == 0) {
    av0[n] = a0; av1[n] = a1; bv0[n] = b0; bv1[n] = b1; u[n] = uu;
    float c40 = coef[4 * 2 + 0], c41 = coef[4 * 2 + 1];
    selfy[n] = c40 * (a0 + b0) + c41 * (a1 + b1) + wvb[0];
  }
}

// ---------------- edge kernel: both directions, atomic f32 aggregate ----------------
__global__ void __launch_bounds__(256) k_edges(const int* src, const int* dst, const int* et,
                        const float* coef, const float* wvb, const float* Pk0,
                        const float* Pk1, const float* q, const float* t0,
                        const float* t1, const float* u, const float* av0,
                        const float* av1, const float* bv0, const float* bv1,
                        float* wvin, float* zin, float* wvout, float* zout) {
  int wid = threadIdx.x >> 6, lane = threadIdx.x & 63;
  long e = (long)blockIdx.x * 4 + wid;
  if (e >= NE) return;
  int s = src[e], d = dst[e], t = et[e];
  float c0 = coef[t * 2], c1 = coef[t * 2 + 1];
  size_t sb = (size_t)s * DD + 2 * lane, db = (size_t)d * DD + 2 * lane;
  float2 p0s = *(const float2*)&Pk0[sb];
  float2 p1s = *(const float2*)&Pk1[sb];
  float2 p0d = *(const float2*)&Pk0[db];
  float2 p1d = *(const float2*)&Pk1[db];
  float2 qs = *(const float2*)&q[sb];
  float2 qd = *(const float2*)&q[db];
  float df = (c0 * p0s.x + c1 * p1s.x) * qd.x + (c0 * p0s.y + c1 * p1s.y) * qd.y;
  float dr = (c0 * p0d.x + c1 * p1d.x) * qs.x + (c0 * p0d.y + c1 * p1d.y) * qs.y;
  for (int off = 32; off; off >>= 1) {
    df += __shfl_xor(df, off);
    dr += __shfl_xor(dr, off);
  }
  if (lane == 0) {
    const float scale = 11.3137084989847604f;  // sqrt(128)
    float wvbd = wvb[0];
    float sf = (df + c0 * t0[d] + c1 * t1[d] + u[d]) / scale;
    sf = fminf(fmaxf(sf, -10.0f), 10.0f);
    float ef = expf(sf);
    float nvf = c0 * (av0[s] + bv0[d]) + c1 * (av1[s] + bv1[d]) + wvbd;
    atomicAdd(&wvin[d], ef * nvf);
    atomicAdd(&zin[d], ef);
    float sr = (dr + c0 * t0[s] + c1 * t1[s] + u[s]) / scale;
    sr = fminf(fmaxf(sr, -10.0f), 10.0f);
    float er = expf(sr);
    float nvr = c0 * (av0[d] + bv0[s]) + c1 * (av1[d] + bv1[s]) + wvbd;
    atomicAdd(&wvout[s], er * nvr);
    atomicAdd(&zout[s], er);
  }
}

// ---------------- y + monotonic u32 key ----------------
__device__ inline unsigned fkey(float f) {
  unsigned b = __float_as_uint(f);
  return (b & 0x80000000u) ? ~b : (b | 0x80000000u);
}

__global__ void k_y(const float* wvin, const float* zin, const float* wvout,
                    const float* zout, const float* selfy, float* y, unsigned* ykey) {
  int n = blockIdx.x * blockDim.x + threadIdx.x;
  if (n < NN) {
    float v = wvin[n] / (zin[n] + 1e-6f) + wvout[n] / (zout[n] + 1e-6f) + selfy[n];
    y[n] = v;
    ykey[n] = fkey(v);
  }
}

// ---------------- exact descending rank via u32 keys ----------------
// rank[i] = #{j : key_j > key_i  or (key_j == key_i and j < i)}
#define RIB 16
#define RITILE 4096   // 256 threads * 16
#define RJCH 1000     // 50 j-chunks * 1000 = 50000
__global__ void __launch_bounds__(256) k_rank2(const unsigned* key, int* rank) {
  __shared__ alignas(16) unsigned ks[RJCH];
  int ilo = blockIdx.x * RITILE;
  int jlo = blockIdx.y * RJCH;
  for (int jj = threadIdx.x; jj < RJCH; jj += 256) ks[jj] = key[jlo + jj];
  __syncthreads();
  int i0 = ilo + threadIdx.x * RIB;
  unsigned ki[RIB];
  int cnt[RIB];
#pragma unroll
  for (int r = 0; r < RIB; r++) {
    int i = i0 + r;
    ki[r] = (i < NN) ? key[i] : 0xFFFFFFFFu;
    cnt[r] = 0;
  }
  if (jlo + RJCH <= ilo) {
    // all j < i : count key_j >= key_i
    for (int jj = 0; jj < RJCH; jj += 4) {
      uint4 kj = *(const uint4*)&ks[jj];
#pragma unroll
      for (int r = 0; r < RIB; r++) {
        cnt[r] += (kj.x >= ki[r]);
        cnt[r] += (kj.y >= ki[r]);
        cnt[r] += (kj.z >= ki[r]);
        cnt[r] += (kj.w >= ki[r]);
      }
    }
  } else if (jlo >= ilo + RITILE) {
    // all j > i : count key_j > key_i
    for (int jj = 0; jj < RJCH; jj += 4) {
      uint4 kj = *(const uint4*)&ks[jj];
#pragma unroll
      for (int r = 0; r < RIB; r++) {
        cnt[r] += (kj.x > ki[r]);
        cnt[r] += (kj.y > ki[r]);
        cnt[r] += (kj.z > ki[r]);
        cnt[r] += (kj.w > ki[r]);
      }
    }
  } else {
    // diagonal: exact condition
    for (int jj = 0; jj < RJCH; jj++) {
      unsigned kj = ks[jj];
      int j = jlo + jj;
#pragma unroll
      for (int r = 0; r < RIB; r++) {
        int i = i0 + r;
        cnt[r] += (kj > ki[r] || (kj == ki[r] && j < i)) ? 1 : 0;
      }
    }
  }
#pragma unroll
  for (int r = 0; r < RIB; r++) {
    int i = i0 + r;
    if (i < NN) atomicAdd(&rank[i], cnt[r]);
  }
}

// ---------------- selection scatter ----------------
__global__ void k_bcnt(const int* rank, int* bcnt) {
  __shared__ int sh[256];
  int i = blockIdx.x * 256 + threadIdx.x;
  int f = (i < NN && rank[i] < KK) ? 1 : 0;
  sh[threadIdx.x] = f;
  __syncthreads();
  for (int off = 128; off; off >>= 1) {
    if (threadIdx.x < off) sh[threadIdx.x] += sh[threadIdx.x + off];
    __syncthreads();
  }
  if (threadIdx.x == 0) bcnt[blockIdx.x] = sh[0];
}

__global__ void k_scan(int* bcnt, int nb) {
  __shared__ int sh[256];
  int t = threadIdx.x;
  int v = (t < nb) ? bcnt[t] : 0;
  sh[t] = v;
  __syncthreads();
  for (int off = 1; off < 256; off <<= 1) {
    int u2 = (t >= off) ? sh[t - off] : 0;
    __syncthreads();
    sh[t] += u2;
    __syncthreads();
  }
  if (t < nb) bcnt[t] = sh[t] - v;  // exclusive
}

__global__ void k_scatter(const int* rank, const int* bcnt, const float* y,
                          float* out_ids, int* selp, float* sig) {
  __shared__ int sh[256];
  int i = blockIdx.x * 256 + threadIdx.x;
  int f = (i < NN && rank[i] < KK) ? 1 : 0;
  sh[threadIdx.x] = f;
  __syncthreads();
  for (int off = 1; off < 256; off <<= 1) {
    int v = (threadIdx.x >= off) ? sh[threadIdx.x - off] : 0;
    __syncthreads();
    sh[threadIdx.x] += v;
    __syncthreads();
  }
  if (f) {
    int slot = bcnt[blockIdx.x] + sh[threadIdx.x] - 1;
    out_ids[slot] = (float)i;
    int p = rank[i];   // position in descending-y list = sel index (faithful quirk)
    selp[slot] = p;
    sig[slot] = 1.0f / (1.0f + expf(-y[p]));
  }
}

__global__ void k_outh(const float* h, const int* selp, const float* sig, float* out) {
  long idx = (long)blockIdx.x * 256 + threadIdx.x;
  if (idx >= (long)KK * DD) return;
  int slot = (int)(idx >> 7), c = (int)(idx & 127);
  int p = selp[slot];
  out[KK + idx] = h[(size_t)p * DD + c] * sig[slot];
}

extern "C" void kernel_launch(void* const* d_in, const int* in_sizes, int n_in,
                              void* d_out, int out_size, void* d_ws, size_t ws_size,
                              hipStream_t stream) {
  const float* h = (const float*)d_in[0];
  const int* src = (const int*)d_in[1];
  const int* dst = (const int*)d_in[2];
  const int* etype = (const int*)d_in[3];
  const float* Wb = (const float*)d_in[4];
  const float* coef = (const float*)d_in[5];
  const float* wqw = (const float*)d_in[6];
  const float* wqb = (const float*)d_in[7];
  const float* wkw = (const float*)d_in[8];
  const float* wkb = (const float*)d_in[9];
  const float* wvw = (const float*)d_in[10];
  const float* wvb = (const float*)d_in[11];
  float* out = (float*)d_out;

  float* W = (float*)d_ws;
  size_t o = 0;
  float* q = W + o;    o += (size_t)NN * DD;
  float* Pk0 = W + o;  o += (size_t)NN * DD;
  float* Pk1 = W + o;  o += (size_t)NN * DD;
  float* Ck0 = W + o;  o += DD * DD;
  float* Ck1 = W + o;  o += DD * DD;
  float* Dk0 = W + o;  o += DD * DD;
  float* Dk1 = W + o;  o += DD * DD;
  float* vecs = W + o; o += 4 * DD;
  float* t0 = W + o;   o += NN;
  float* t1 = W + o;   o += NN;
  float* av0 = W + o;  o += NN;
  float* av1 = W + o;  o += NN;
  float* bv0 = W + o;  o += NN;
  float* bv1 = W + o;  o += NN;
  float* u = W + o;    o += NN;
  float* selfy = W + o; o += NN;
  float* wvin = W + o;  o += NN;  // zero region start (4*NN contiguous)
  float* zin = W + o;   o += NN;
  float* wvout = W + o; o += NN;
  float* zout = W + o;  o += NN;
  float* y = W + o;     o += NN;
  unsigned* ykey = (unsigned*)(W + o); o += NN;
  float* sig = W + o;   o += KK;
  int* ibase = (int*)(W + o);
  int* rank = ibase;
  int* bcnt = ibase + NN;
  int* selp = ibase + NN + 256;

  int nb = (NN + 255) / 256;  // 196
  int gx = (NN + 31) / 32;    // 1563

  k_zero<<<256, 256, 0, stream>>>(wvin, 4 * NN, rank, NN);
  k_smallmats<<<5, 256, 0, stream>>>(Wb, wkw, wvw, Ck0, Ck1, Dk0, Dk1, vecs);
  k_matnode<<<gx, 256, 0, stream>>>(h, wqw, wqb, nullptr, q, nullptr);
  k_matnode<<<gx, 256, 0, stream>>>(h, Ck0, nullptr, nullptr, Pk0, nullptr);
  k_matnode<<<gx, 256, 0, stream>>>(h, Ck1, nullptr, nullptr, Pk1, nullptr);
  k_matnode<<<gx, 256, 0, stream>>>(h, Dk0, nullptr, q, nullptr, t0);
  k_matnode<<<gx, 256, 0, stream>>>(h, Dk1, nullptr, q, nullptr, t1);
  k_nodescalars<<<(NN + 3) / 4, 256, 0, stream>>>(h, q, vecs, wkb, coef, wvb, av0, av1,
                                                  bv0, bv1, u, selfy);
  k_edges<<<NE / 4, 256, 0, stream>>>(src, dst, etype, coef, wvb, Pk0, Pk1, q, t0, t1, u,
                                      av0, av1, bv0, bv1, wvin, zin, wvout, zout);
  k_y<<<nb, 256, 0, stream>>>(wvin, zin, wvout, zout, selfy, y, ykey);
  k_rank2<<<dim3((NN + RITILE - 1) / RITILE, NN / RJCH), 256, 0, stream>>>(ykey, rank);
  k_bcnt<<<nb, 256, 0, stream>>>(rank, bcnt);
  k_scan<<<1, 256, 0, stream>>>(bcnt, nb);
  k_scatter<<<nb, 256, 0, stream>>>(rank, bcnt, y, out, selp, sig);
  k_outh<<<(KK * DD) / 256, 256, 0, stream>>>(h, selp, sig, out);
}

// Round 3
// 882.019 us; speedup vs baseline: 2.1186x; 1.4582x over previous
//
#include <hip/hip_runtime.h>

#define NN 50000
#define NE 500000
#define DD 128
#define KK 25000

__device__ inline unsigned short f2bf(float x) {
  unsigned u = __float_as_uint(x);
  unsigned r = (u + 0x7FFFu + ((u >> 16) & 1u)) >> 16;
  return (unsigned short)r;
}
__device__ inline float bf2f(unsigned short b) {
  return __uint_as_float(((unsigned)b) << 16);
}

// ---------------- zero init ----------------
__global__ void k_zero(float* zf, int nf, int* zi, int ni) {
  int i = blockIdx.x * blockDim.x + threadIdx.x;
  int stride = gridDim.x * blockDim.x;
  for (int k = i; k < nf; k += stride) zf[k] = 0.0f;
  for (int k = i; k < ni; k += stride) zi[k] = 0;
}

// ---------------- small composed matrices (f32) ----------------
__global__ void k_smallmats(const float* Wb, const float* wkw, const float* wvw,
                            float* Ck0, float* Ck1, float* Dk0, float* Dk1,
                            float* vecs) {
  int b = blockIdx.x, tid = threadIdx.x;
  if (b < 4) {
    int basis = b & 1;
    int rowoff = (b >> 1) * DD;
    float* outp = (b == 0) ? Ck0 : ((b == 1) ? Ck1 : ((b == 2) ? Dk0 : Dk1));
    for (int idx = tid; idx < DD * DD; idx += blockDim.x) {
      int i = idx >> 7, t = idx & 127;
      const float* wrow = Wb + (size_t)(basis * 2 * DD + rowoff + i) * DD;
      float s = 0.0f;
      for (int m = 0; m < DD; m++) s += wrow[m] * wkw[m * DD + t];
      outp[idx] = s;
    }
  } else {
    for (int idx = tid; idx < 4 * DD; idx += blockDim.x) {
      int which = idx >> 7, i = idx & 127;
      int basis = which & 1, rowoff = (which >> 1) * DD;
      const float* wrow = Wb + (size_t)(basis * 2 * DD + rowoff + i) * DD;
      float s = 0.0f;
      for (int m = 0; m < DD; m++) s += wrow[m] * wvw[m];
      vecs[which * DD + i] = s;
    }
  }
}

// ---------------- fused node-level matvec ----------------
// MODE 0: outq[n][:] = h[n]@M0 + bias
// MODE 1: PK01[n][k][2] = bf16(h[n]@M0)[k], bf16(h[n]@M1)[k]
// MODE 2: t0[n] = (h[n]@M0)·q[n], t1[n] = (h[n]@M1)·q[n]
template <int MODE>
__global__ void __launch_bounds__(256) k_matnode2(
    const float* __restrict__ h, const float* __restrict__ M0,
    const float* __restrict__ M1, const float* __restrict__ bias,
    const float* __restrict__ q_in, float* __restrict__ outq,
    unsigned short* __restrict__ outpk, float* __restrict__ outt0,
    float* __restrict__ outt1) {
  __shared__ float hs[32 * DD];
  __shared__ float red[8];
  int tid = threadIdx.x;
  int n0 = blockIdx.x * 32;
  for (int idx = tid; idx < 32 * DD; idx += 256) {
    int n = n0 + (idx >> 7);
    hs[idx] = (n < NN) ? h[(size_t)n * DD + (idx & 127)] : 0.0f;
  }
  __syncthreads();
  int col = tid & 127, half = tid >> 7;
  float acc0[16], acc1[16];
#pragma unroll
  for (int j = 0; j < 16; j++) { acc0[j] = 0.0f; acc1[j] = 0.0f; }
  for (int k4 = 0; k4 < DD / 4; k4++) {
    float a0 = M0[(4 * k4 + 0) * DD + col];
    float a1 = M0[(4 * k4 + 1) * DD + col];
    float a2 = M0[(4 * k4 + 2) * DD + col];
    float a3 = M0[(4 * k4 + 3) * DD + col];
    float b0 = 0.f, b1 = 0.f, b2 = 0.f, b3 = 0.f;
    if (MODE != 0) {
      b0 = M1[(4 * k4 + 0) * DD + col];
      b1 = M1[(4 * k4 + 1) * DD + col];
      b2 = M1[(4 * k4 + 2) * DD + col];
      b3 = M1[(4 * k4 + 3) * DD + col];
    }
#pragma unroll
    for (int j = 0; j < 16; j++) {
      const float4 hv = *(const float4*)&hs[(half * 16 + j) * DD + 4 * k4];
      acc0[j] += hv.x * a0 + hv.y * a1 + hv.z * a2 + hv.w * a3;
      if (MODE != 0) acc1[j] += hv.x * b0 + hv.y * b1 + hv.z * b2 + hv.w * b3;
    }
  }
  if (MODE == 0) {
    for (int j = 0; j < 16; j++) {
      int n = n0 + half * 16 + j;
      if (n < NN) outq[(size_t)n * DD + col] = acc0[j] + bias[col];
    }
  } else if (MODE == 1) {
    for (int j = 0; j < 16; j++) {
      int n = n0 + half * 16 + j;
      if (n < NN) {
        ushort2 st;
        st.x = f2bf(acc0[j]);
        st.y = f2bf(acc1[j]);
        *(ushort2*)&outpk[(size_t)n * 256 + 2 * col] = st;
      }
    }
  } else {
    int lane = tid & 63, wid = tid >> 6;
    for (int j = 0; j < 16; j++) {
      int n = n0 + half * 16 + j;
      float qv = (n < NN) ? q_in[(size_t)n * DD + col] : 0.0f;
      float v0 = acc0[j] * qv, v1 = acc1[j] * qv;
      for (int off = 32; off; off >>= 1) {
        v0 += __shfl_xor(v0, off);
        v1 += __shfl_xor(v1, off);
      }
      if (lane == 0) { red[wid * 2] = v0; red[wid * 2 + 1] = v1; }
      __syncthreads();
      if (tid == 0) {
        int na = n0 + j;
        if (na < NN) { outt0[na] = red[0] + red[2]; outt1[na] = red[1] + red[3]; }
      }
      if (tid == 1) {
        int nb2 = n0 + 16 + j;
        if (nb2 < NN) { outt0[nb2] = red[4] + red[6]; outt1[nb2] = red[5] + red[7]; }
      }
      __syncthreads();
    }
  }
}

// ---------------- per-node scalars (+ bf16 pack of q) ----------------
__global__ void k_nodescalars(const float* h, const float* q, const float* vecs,
                              const float* wkb, const float* coef, const float* wvb,
                              float* av0, float* av1, float* bv0, float* bv1,
                              float* u, float* selfy, unsigned short* qe) {
  int wid = threadIdx.x >> 6, lane = threadIdx.x & 63;
  int n = blockIdx.x * 4 + wid;
  if (n >= NN) return;
  const float* avv0 = vecs;
  const float* avv1 = vecs + DD;
  const float* bvv0 = vecs + 2 * DD;
  const float* bvv1 = vecs + 3 * DD;
  float h0 = h[(size_t)n * DD + lane], h1 = h[(size_t)n * DD + 64 + lane];
  float q0 = q[(size_t)n * DD + lane], q1 = q[(size_t)n * DD + 64 + lane];
  qe[(size_t)n * DD + lane] = f2bf(q0);
  qe[(size_t)n * DD + 64 + lane] = f2bf(q1);
  float a0 = h0 * avv0[lane] + h1 * avv0[64 + lane];
  float a1 = h0 * avv1[lane] + h1 * avv1[64 + lane];
  float b0 = h0 * bvv0[lane] + h1 * bvv0[64 + lane];
  float b1 = h0 * bvv1[lane] + h1 * bvv1[64 + lane];
  float uu = q0 * wkb[lane] + q1 * wkb[64 + lane];
  for (int off = 32; off; off >>= 1) {
    a0 += __shfl_xor(a0, off); a1 += __shfl_xor(a1, off);
    b0 += __shfl_xor(b0, off); b1 += __shfl_xor(b1, off);
    uu += __shfl_xor(uu, off);
  }
  if (lane == 0) {
    av0[n] = a0; av1[n] = a1; bv0[n] = b0; bv1[n] = b1; u[n] = uu;
    float c40 = coef[4 * 2 + 0], c41 = coef[4 * 2 + 1];
    selfy[n] = c40 * (a0 + b0) + c41 * (a1 + b1) + wvb[0];
  }
}

// ---------------- edge kernel: bf16 gathers, f32 accumulate ----------------
__global__ void __launch_bounds__(256) k_edges(
    const int* src, const int* dst, const int* et, const float* coef,
    const float* wvb, const unsigned short* __restrict__ PK,
    const unsigned short* __restrict__ QE, const float* t0, const float* t1,
    const float* u, const float* av0, const float* av1, const float* bv0,
    const float* bv1, float* wvin, float* zin, float* wvout, float* zout) {
  int wid = threadIdx.x >> 6, lane = threadIdx.x & 63;
  long e = (long)blockIdx.x * 4 + wid;
  if (e >= NE) return;
  int s = src[e], d = dst[e], t = et[e];
  float c0 = coef[t * 2], c1 = coef[t * 2 + 1];
  ushort4 pks = *(const ushort4*)&PK[(size_t)s * 256 + 4 * lane];
  ushort4 pkd = *(const ushort4*)&PK[(size_t)d * 256 + 4 * lane];
  ushort2 qse = *(const ushort2*)&QE[(size_t)s * DD + 2 * lane];
  ushort2 qde = *(const ushort2*)&QE[(size_t)d * DD + 2 * lane];
  float df = (c0 * bf2f(pks.x) + c1 * bf2f(pks.y)) * bf2f(qde.x) +
             (c0 * bf2f(pks.z) + c1 * bf2f(pks.w)) * bf2f(qde.y);
  float dr = (c0 * bf2f(pkd.x) + c1 * bf2f(pkd.y)) * bf2f(qse.x) +
             (c0 * bf2f(pkd.z) + c1 * bf2f(pkd.w)) * bf2f(qse.y);
  for (int off = 32; off; off >>= 1) {
    df += __shfl_xor(df, off);
    dr += __shfl_xor(dr, off);
  }
  if (lane == 0) {
    const float scale = 11.3137084989847604f;  // sqrt(128)
    float wvbd = wvb[0];
    float sf = (df + c0 * t0[d] + c1 * t1[d] + u[d]) / scale;
    sf = fminf(fmaxf(sf, -10.0f), 10.0f);
    float ef = expf(sf);
    float nvf = c0 * (av0[s] + bv0[d]) + c1 * (av1[s] + bv1[d]) + wvbd;
    atomicAdd(&wvin[d], ef * nvf);
    atomicAdd(&zin[d], ef);
    float sr = (dr + c0 * t0[s] + c1 * t1[s] + u[s]) / scale;
    sr = fminf(fmaxf(sr, -10.0f), 10.0f);
    float er = expf(sr);
    float nvr = c0 * (av0[d] + bv0[s]) + c1 * (av1[d] + bv1[s]) + wvbd;
    atomicAdd(&wvout[s], er * nvr);
    atomicAdd(&zout[s], er);
  }
}

// ---------------- y + monotonic u32 key ----------------
__device__ inline unsigned fkey(float f) {
  unsigned b = __float_as_uint(f);
  return (b & 0x80000000u) ? ~b : (b | 0x80000000u);
}

__global__ void k_y(const float* wvin, const float* zin, const float* wvout,
                    const float* zout, const float* selfy, float* y, unsigned* ykey) {
  int n = blockIdx.x * blockDim.x + threadIdx.x;
  if (n < NN) {
    float v = wvin[n] / (zin[n] + 1e-6f) + wvout[n] / (zout[n] + 1e-6f) + selfy[n];
    y[n] = v;
    ykey[n] = fkey(v);
  }
}

// ---------------- exact descending rank via u32 keys ----------------
// rank[i] = #{j : key_j > key_i  or (key_j == key_i and j < i)}
#define RIB 4
#define RITILE 1024  // 256 threads * 4
#define RJB 42
#define RJCH 1200    // 42 * 1200 = 50400 >= NN
__global__ void __launch_bounds__(256) k_rank2(const unsigned* __restrict__ key,
                                               int* __restrict__ rank) {
  __shared__ alignas(16) unsigned ks[RJCH];
  int ilo = blockIdx.x * RITILE;
  int jlo = blockIdx.y * RJCH;
  for (int jj = threadIdx.x; jj < RJCH; jj += 256) {
    int j = jlo + jj;
    ks[jj] = (j < NN) ? key[j] : 0u;  // key 0 < any real key -> never counted
  }
  __syncthreads();
  int i0 = ilo + threadIdx.x * RIB;
  unsigned ki[RIB];
  int cnt[RIB];
#pragma unroll
  for (int r = 0; r < RIB; r++) {
    int i = i0 + r;
    ki[r] = (i < NN) ? key[i] : 0xFFFFFFFFu;
    cnt[r] = 0;
  }
  if (jlo + RJCH <= ilo) {
    // all j < i : count key_j >= key_i
    for (int jj = 0; jj < RJCH; jj += 4) {
      uint4 kj = *(const uint4*)&ks[jj];
#pragma unroll
      for (int r = 0; r < RIB; r++) {
        cnt[r] += (kj.x >= ki[r]);
        cnt[r] += (kj.y >= ki[r]);
        cnt[r] += (kj.z >= ki[r]);
        cnt[r] += (kj.w >= ki[r]);
      }
    }
  } else if (jlo >= ilo + RITILE) {
    // all j > i : count key_j > key_i
    for (int jj = 0; jj < RJCH; jj += 4) {
      uint4 kj = *(const uint4*)&ks[jj];
#pragma unroll
      for (int r = 0; r < RIB; r++) {
        cnt[r] += (kj.x > ki[r]);
        cnt[r] += (kj.y > ki[r]);
        cnt[r] += (kj.z > ki[r]);
        cnt[r] += (kj.w > ki[r]);
      }
    }
  } else {
    for (int jj = 0; jj < RJCH; jj++) {
      unsigned kj = ks[jj];
      int j = jlo + jj;
#pragma unroll
      for (int r = 0; r < RIB; r++) {
        int i = i0 + r;
        cnt[r] += (kj > ki[r] || (kj == ki[r] && j < i)) ? 1 : 0;
      }
    }
  }
#pragma unroll
  for (int r = 0; r < RIB; r++) {
    int i = i0 + r;
    if (i < NN) atomicAdd(&rank[i], cnt[r]);
  }
}

// ---------------- selection scatter ----------------
__global__ void k_bcnt(const int* rank, int* bcnt) {
  __shared__ int sh[256];
  int i = blockIdx.x * 256 + threadIdx.x;
  int f = (i < NN && rank[i] < KK) ? 1 : 0;
  sh[threadIdx.x] = f;
  __syncthreads();
  for (int off = 128; off; off >>= 1) {
    if (threadIdx.x < off) sh[threadIdx.x] += sh[threadIdx.x + off];
    __syncthreads();
  }
  if (threadIdx.x == 0) bcnt[blockIdx.x] = sh[0];
}

__global__ void k_scan(int* bcnt, int nb) {
  __shared__ int sh[256];
  int t = threadIdx.x;
  int v = (t < nb) ? bcnt[t] : 0;
  sh[t] = v;
  __syncthreads();
  for (int off = 1; off < 256; off <<= 1) {
    int u2 = (t >= off) ? sh[t - off] : 0;
    __syncthreads();
    sh[t] += u2;
    __syncthreads();
  }
  if (t < nb) bcnt[t] = sh[t] - v;  // exclusive
}

__global__ void k_scatter(const int* rank, const int* bcnt, const float* y,
                          float* out_ids, int* selp, float* sig) {
  __shared__ int sh[256];
  int i = blockIdx.x * 256 + threadIdx.x;
  int f = (i < NN && rank[i] < KK) ? 1 : 0;
  sh[threadIdx.x] = f;
  __syncthreads();
  for (int off = 1; off < 256; off <<= 1) {
    int v = (threadIdx.x >= off) ? sh[threadIdx.x - off] : 0;
    __syncthreads();
    sh[threadIdx.x] += v;
    __syncthreads();
  }
  if (f) {
    int slot = bcnt[blockIdx.x] + sh[threadIdx.x] - 1;
    out_ids[slot] = (float)i;
    int p = rank[i];  // position in descending-y list = sel index (faithful quirk)
    selp[slot] = p;
    sig[slot] = 1.0f / (1.0f + expf(-y[p]));
  }
}

__global__ void k_outh(const float* h, const int* selp, const float* sig, float* out) {
  long idx = (long)blockIdx.x * 256 + threadIdx.x;
  if (idx >= (long)KK * DD) return;
  int slot = (int)(idx >> 7), c = (int)(idx & 127);
  int p = selp[slot];
  out[KK + idx] = h[(size_t)p * DD + c] * sig[slot];
}

extern "C" void kernel_launch(void* const* d_in, const int* in_sizes, int n_in,
                              void* d_out, int out_size, void* d_ws, size_t ws_size,
                              hipStream_t stream) {
  const float* h = (const float*)d_in[0];
  const int* src = (const int*)d_in[1];
  const int* dst = (const int*)d_in[2];
  const int* etype = (const int*)d_in[3];
  const float* Wb = (const float*)d_in[4];
  const float* coef = (const float*)d_in[5];
  const float* wqw = (const float*)d_in[6];
  const float* wqb = (const float*)d_in[7];
  const float* wkw = (const float*)d_in[8];
  const float* wkb = (const float*)d_in[9];
  const float* wvw = (const float*)d_in[10];
  const float* wvb = (const float*)d_in[11];
  float* out = (float*)d_out;

  float* W = (float*)d_ws;
  size_t o = 0;
  float* q = W + o;    o += (size_t)NN * DD;
  unsigned short* PK01 = (unsigned short*)(W + o); o += (size_t)NN * DD;  // bf16 [n][128][2]
  unsigned short* qe = (unsigned short*)(W + o);   o += (size_t)NN * DD / 2;  // bf16 [n][128]
  float* Ck0 = W + o;  o += DD * DD;
  float* Ck1 = W + o;  o += DD * DD;
  float* Dk0 = W + o;  o += DD * DD;
  float* Dk1 = W + o;  o += DD * DD;
  float* vecs = W + o; o += 4 * DD;
  float* t0 = W + o;   o += NN;
  float* t1 = W + o;   o += NN;
  float* av0 = W + o;  o += NN;
  float* av1 = W + o;  o += NN;
  float* bv0 = W + o;  o += NN;
  float* bv1 = W + o;  o += NN;
  float* u = W + o;    o += NN;
  float* selfy = W + o; o += NN;
  float* wvin = W + o;  o += NN;  // zero region start (4*NN contiguous)
  float* zin = W + o;   o += NN;
  float* wvout = W + o; o += NN;
  float* zout = W + o;  o += NN;
  float* y = W + o;     o += NN;
  unsigned* ykey = (unsigned*)(W + o); o += NN;
  float* sig = W + o;   o += KK;
  int* ibase = (int*)(W + o);
  int* rank = ibase;
  int* bcnt = ibase + NN;
  int* selp = ibase + NN + 256;

  int nb = (NN + 255) / 256;  // 196
  int gx = (NN + 31) / 32;    // 1563

  k_zero<<<256, 256, 0, stream>>>(wvin, 4 * NN, rank, NN);
  k_smallmats<<<5, 256, 0, stream>>>(Wb, wkw, wvw, Ck0, Ck1, Dk0, Dk1, vecs);
  k_matnode2<0><<<gx, 256, 0, stream>>>(h, wqw, nullptr, wqb, nullptr, q, nullptr,
                                        nullptr, nullptr);
  k_matnode2<1><<<gx, 256, 0, stream>>>(h, Ck0, Ck1, nullptr, nullptr, nullptr, PK01,
                                        nullptr, nullptr);
  k_matnode2<2><<<gx, 256, 0, stream>>>(h, Dk0, Dk1, nullptr, q, nullptr, nullptr,
                                        t0, t1);
  k_nodescalars<<<(NN + 3) / 4, 256, 0, stream>>>(h, q, vecs, wkb, coef, wvb, av0, av1,
                                                  bv0, bv1, u, selfy, qe);
  k_edges<<<NE / 4, 256, 0, stream>>>(src, dst, etype, coef, wvb, PK01, qe, t0, t1, u,
                                      av0, av1, bv0, bv1, wvin, zin, wvout, zout);
  k_y<<<nb, 256, 0, stream>>>(wvin, zin, wvout, zout, selfy, y, ykey);
  k_rank2<<<dim3((NN + RITILE - 1) / RITILE, RJB), 256, 0, stream>>>(ykey, rank);
  k_bcnt<<<nb, 256, 0, stream>>>(rank, bcnt);
  k_scan<<<1, 256, 0, stream>>>(bcnt, nb);
  k_scatter<<<nb, 256, 0, stream>>>(rank, bcnt, y, out, selp, sig);
  k_outh<<<(KK * DD) / 256, 256, 0, stream>>>(h, selp, sig, out);
}